// Round 6
// baseline (20444.708 us; speedup 1.0000x reference)
//
#include <hip/hip_runtime.h>
#include <cstddef>

#define BB 32
#define TT 512
#define HH 512
#define NBLK 256
#define NTHR 512
#define AG __HIP_MEMORY_SCOPE_AGENT

// ---------------------------------------------------------------------------
// Persistent GRU, 2 layers software-pipelined (layer 1 lags 1 step).
//
// Coherence protocol (round-5: FENCE-FREE, no cache invalidation ever):
//   - ALL mutable state (h, rh, uu, y0, barrier counters) accessed ONLY via
//     relaxed AGENT-scope atomic loads/stores -> sc-flagged, bypass the
//     non-coherent L1/L2, served at the device-coherent point (L3). Always
//     fresh; no acquire, no buffer_inv.
//   - Immutable data (x, Wg, Wc, WcT, bg, bc, seq_lens) -> plain cached
//     loads; L2 is never invalidated so it stays hot the whole kernel.
//   - Store->barrier ordering: __syncthreads() drains vmcnt(0) (compiler-
//     guaranteed before s_barrier), so sc stores are globally complete
//     before the arrival add is issued. (Same mechanism round 4 validated.)
//
// Work decomposition (interleaved-K so scalar sc loads coalesce):
//   256 blocks x 512 thr (8 waves = 2 waves/SIMD at 1 block/CU).
//   l = blk>>7, cg = blk&127. Gates: cols [8cg,8cg+8); cand: [4cg,4cg+4).
//   Wave w handles batches [4w, 4w+4). Lane L owns k in {L, L+64, ..., L+960}
//   (16 ks: i<8 -> input half d=L+64i, i>=8 -> h half d=L+64(i-8)).
//   Per-lane gate weights (8 cols x 16 k = 128 VGPR) loaded ONCE at startup
//   straight from Wg[k][j] (uncoalesced but one-time, L3-absorbed).
//   Cand weights (4x16) reloaded per step from WcT[m][k] (coalesced, L2-hot)
//   to cap register pressure. Dots finished with select-merge butterflies:
//   red8 -> lane&7 holds col gj0+(lane&7); red4 -> lane&3 holds cj0+(lane&3).
//
// Barrier: two-level tree. 32 leaf counters (16B-spaced ints; 8 arrivals
// each) + 1 root (32 arrivals by leaf-waiter blocks 0..31). Monotonic
// targets, no reset. 2 barriers/step, 1026 total.
//
// ws (floats): h0@0[16384] h1@16384 y0@32768[2][32][512] rh@65536[2*16384]
//   uu@98304[2*16384] bar@131072[256 f: leaf i at int 4i, root at int 128]
//   WcT@131328 [2][512][1024] (WcT[l][m][k] = Wc[l][k][m])
// ---------------------------------------------------------------------------

template <int R, int C>
__global__ __launch_bounds__(256) void transpose_k(const float* __restrict__ src,
                                                   float* __restrict__ dst) {
    __shared__ float tile[32][33];
    const int tx = threadIdx.x & 31;
    const int ty = threadIdx.x >> 5;
    const int tiles_c = C / 32;
    const int bc_ = blockIdx.x % tiles_c;
    const int br_ = blockIdx.x / tiles_c;
    const int r0 = br_ * 32, c0 = bc_ * 32;
#pragma unroll
    for (int k = 0; k < 32; k += 8)
        tile[ty + k][tx] = src[(size_t)(r0 + ty + k) * C + (c0 + tx)];
    __syncthreads();
#pragma unroll
    for (int k = 0; k < 32; k += 8)
        dst[(size_t)(c0 + ty + k) * R + (r0 + tx)] = tile[tx][ty + k];
}

__device__ __forceinline__ float scld(const float* p) {
    return __hip_atomic_load(p, __ATOMIC_RELAXED, AG);
}
__device__ __forceinline__ void scst(float* p, float v) {
    __hip_atomic_store(p, v, __ATOMIC_RELAXED, AG);
}

// Reduce 8 accumulators over 64 lanes; lane ends with total of acc[lane&7].
__device__ __forceinline__ float red8(float a0, float a1, float a2, float a3,
                                      float a4, float a5, float a6, float a7,
                                      int lane) {
    const bool b1 = lane & 1, b2 = lane & 2, b4 = lane & 4;
    float p0 = (b1 ? a1 : a0) + __shfl_xor((b1 ? a0 : a1), 1, 64);
    float p1 = (b1 ? a3 : a2) + __shfl_xor((b1 ? a2 : a3), 1, 64);
    float p2 = (b1 ? a5 : a4) + __shfl_xor((b1 ? a4 : a5), 1, 64);
    float p3 = (b1 ? a7 : a6) + __shfl_xor((b1 ? a6 : a7), 1, 64);
    float q0 = (b2 ? p1 : p0) + __shfl_xor((b2 ? p0 : p1), 2, 64);
    float q1 = (b2 ? p3 : p2) + __shfl_xor((b2 ? p2 : p3), 2, 64);
    float r = (b4 ? q1 : q0) + __shfl_xor((b4 ? q0 : q1), 4, 64);
    r += __shfl_xor(r, 8, 64);
    r += __shfl_xor(r, 16, 64);
    r += __shfl_xor(r, 32, 64);
    return r;
}

// Reduce 4 accumulators; lane ends with total of acc[lane&3].
__device__ __forceinline__ float red4(float a0, float a1, float a2, float a3,
                                      int lane) {
    const bool b1 = lane & 1, b2 = lane & 2;
    float p0 = (b1 ? a1 : a0) + __shfl_xor((b1 ? a0 : a1), 1, 64);
    float p1 = (b1 ? a3 : a2) + __shfl_xor((b1 ? a2 : a3), 1, 64);
    float r = (b2 ? p1 : p0) + __shfl_xor((b2 ? p0 : p1), 2, 64);
    r += __shfl_xor(r, 4, 64);
    r += __shfl_xor(r, 8, 64);
    r += __shfl_xor(r, 16, 64);
    r += __shfl_xor(r, 32, 64);
    return r;
}

// Two-level barrier: leaves at barb[4*(bid&31)], root at barb[128].
__device__ __forceinline__ void gbar(int* barb, int bid, int nbar) {
    __syncthreads();  // vmcnt(0) drain: sc stores globally complete
    if (threadIdx.x == 0) {
        __hip_atomic_fetch_add(&barb[(bid & 31) * 4], 1, __ATOMIC_RELAXED, AG);
        if (bid < 32) {
            const int lt = nbar * 8;
            while (__hip_atomic_load(&barb[bid * 4], __ATOMIC_RELAXED, AG) < lt)
                __builtin_amdgcn_s_sleep(1);
            __hip_atomic_fetch_add(&barb[128], 1, __ATOMIC_RELAXED, AG);
        }
        const int rt = nbar * 32;
        while (__hip_atomic_load(&barb[128], __ATOMIC_RELAXED, AG) < rt)
            __builtin_amdgcn_s_sleep(1);
    }
    __syncthreads();
}

__global__ __launch_bounds__(NTHR, 2) void rnn_persist(
    const float* __restrict__ x, const int* __restrict__ seq_lens,
    const float* __restrict__ Wg, const float* __restrict__ bg,
    const float* __restrict__ WcT, const float* __restrict__ bc,
    float* __restrict__ out, float* __restrict__ ws) {
    float* h0 = ws;
    float* h1 = ws + 16384;
    float* y0 = ws + 32768;
    float* rh = ws + 65536;
    float* uu = ws + 98304;
    int* barb = (int*)(ws + 131072);

    const int bid = blockIdx.x;
    const int l = bid >> 7;
    const int cg = bid & 127;
    const int w = threadIdx.x >> 6;
    const int lane = threadIdx.x & 63;
    const int gj0 = cg * 8;
    const int cj0 = cg * 4;

    float* __restrict__ hl = l ? h1 : h0;
    float* __restrict__ rhl = rh + (size_t)l * (BB * HH);
    float* __restrict__ uul = uu + (size_t)l * (BB * HH);

    // One-time gate-weight load into 128 VGPRs: wg[c][i] = Wg[l][lane+64i][gj0+c].
    float wg[8][16];
#pragma unroll
    for (int c = 0; c < 8; ++c)
#pragma unroll
        for (int i = 0; i < 16; ++i)
            wg[c][i] = Wg[((size_t)l * 1024 + lane + 64 * i) * 1024 + gj0 + c];
    const float bgj = bg[l * 1024 + gj0 + (lane & 7)];
    const float bcm = bc[l * 512 + cj0 + (lane & 3)];
    const float* wcp = WcT + ((size_t)l * 512 + cj0) * 1024 + lane;  // +64*i, +1024*c

    int nbar = 1;
    for (int t = 0; t <= TT; ++t) {
        const int tt = t - l;
        const bool active = (tt >= 0) && (tt < TT);

        // ---------------- phase A: gates ----------------
        if (active) {
            for (int bi = 0; bi < 4; ++bi) {
                const int b = w * 4 + bi;
                const float* xrow = x + ((size_t)b * TT + tt) * HH;
                const float* yrow = y0 + ((size_t)((tt & 1) * BB + b)) * HH;
                const float* hrow = hl + (size_t)b * HH;
                float v[16];
#pragma unroll
                for (int i = 0; i < 8; ++i)
                    v[i] = l ? scld(yrow + lane + 64 * i) : xrow[lane + 64 * i];
#pragma unroll
                for (int i = 0; i < 8; ++i)
                    v[8 + i] = scld(hrow + lane + 64 * i);
                float acc[8] = {0, 0, 0, 0, 0, 0, 0, 0};
#pragma unroll
                for (int i = 0; i < 16; ++i) {
                    const float vi = v[i];
#pragma unroll
                    for (int c = 0; c < 8; ++c) acc[c] = fmaf(vi, wg[c][i], acc[c]);
                }
                const float sum = red8(acc[0], acc[1], acc[2], acc[3],
                                       acc[4], acc[5], acc[6], acc[7], lane);
                if (lane < 8) {
                    const int j = gj0 + lane;
                    const float g = 1.0f / (1.0f + __expf(-(sum + bgj)));
                    if (gj0 < HH)
                        scst(rhl + (size_t)b * HH + j, g * scld(hrow + j));
                    else
                        scst(uul + (size_t)b * HH + (j - HH), g);
                }
            }
        }
        gbar(barb, bid, nbar); ++nbar;

        // ---------------- phase B: candidate + update ----------------
        if (active) {
            // reload cand weights (coalesced, L2-hot, immutable)
            float wc[4][16];
#pragma unroll
            for (int c = 0; c < 4; ++c)
#pragma unroll
                for (int i = 0; i < 16; ++i)
                    wc[c][i] = wcp[(size_t)c * 1024 + 64 * i];
#pragma unroll 2
            for (int bi = 0; bi < 4; ++bi) {
                const int b = w * 4 + bi;
                const float* xrow = x + ((size_t)b * TT + tt) * HH;
                const float* yrow = y0 + ((size_t)((tt & 1) * BB + b)) * HH;
                const float* rrow = rhl + (size_t)b * HH;
                float v[16];
#pragma unroll
                for (int i = 0; i < 8; ++i)
                    v[i] = l ? scld(yrow + lane + 64 * i) : xrow[lane + 64 * i];
#pragma unroll
                for (int i = 0; i < 8; ++i)
                    v[8 + i] = scld(rrow + lane + 64 * i);
                float acc[4] = {0, 0, 0, 0};
#pragma unroll
                for (int i = 0; i < 16; ++i) {
                    const float vi = v[i];
#pragma unroll
                    for (int c = 0; c < 4; ++c) acc[c] = fmaf(vi, wc[c][i], acc[c]);
                }
                const float sum = red4(acc[0], acc[1], acc[2], acc[3], lane);
                if (lane < 4) {
                    const int m = cj0 + lane;
                    const float c = tanhf(sum + bcm);
                    const float u = scld(uul + (size_t)b * HH + m);
                    const float hold = scld(hl + (size_t)b * HH + m);
                    const bool act = tt < seq_lens[b];
                    const float hn = u * hold + (1.0f - u) * c;
                    scst(hl + (size_t)b * HH + m, act ? hn : hold);
                    const float yv = act ? hn : 0.0f;
                    if (l == 0)
                        scst(y0 + ((size_t)((tt & 1) * BB + b)) * HH + m, yv);
                    else
                        out[((size_t)b * TT + tt) * HH + m] = yv;
                }
            }
        }
        gbar(barb, bid, nbar); ++nbar;
    }
}

extern "C" void kernel_launch(void* const* d_in, const int* in_sizes, int n_in,
                              void* d_out, int out_size, void* d_ws, size_t ws_size,
                              hipStream_t stream) {
    const float* x = (const float*)d_in[0];
    const int* seq_lens = (const int*)d_in[1];
    const float* Wg = (const float*)d_in[2];
    const float* bg = (const float*)d_in[3];
    const float* Wc = (const float*)d_in[4];
    const float* bc = (const float*)d_in[5];
    float* out = (float*)d_out;
    float* ws = (float*)d_ws;

    float* WcT = ws + 131328;

    // zero state + barrier counters every launch (graph replays deterministic)
    hipMemsetAsync(ws, 0, 131328 * sizeof(float), stream);

    // transpose cand weights only: WcT[l][m][k] = Wc[l][k][m]
    transpose_k<1024, 512><<<512, 256, 0, stream>>>(Wc, WcT);
    transpose_k<1024, 512><<<512, 256, 0, stream>>>(Wc + 1024 * 512, WcT + 512 * 1024);

    rnn_persist<<<NBLK, NTHR, 0, stream>>>(x, seq_lens, Wg, bg, WcT, bc, out, ws);
}

// Round 7
// 9020.358 us; speedup vs baseline: 2.2665x; 2.2665x over previous
//
#include <hip/hip_runtime.h>
#include <cstddef>

#define BB 32
#define TT 512
#define HH 512
#define NBLK 256
#define NTHR 512
#define AG __HIP_MEMORY_SCOPE_AGENT

// ---------------------------------------------------------------------------
// Persistent GRU, 2 layers pipelined, XCD-LOCAL batch partitioning (round 6).
//
// Key idea: per-XCD L2 is coherent WITHIN the XCD. Partition so each
// (layer, batch-group-of-8) lives entirely on one XCD:
//   - h/rh/uu: normal stores (dirty local L2) + sc0 loads (L1-bypass, L2 hit)
//     -> no L3 traffic at all for the big per-step state broadcast.
//   - y0 (layer0 -> layer1 handoff): sc1 (agent) stores/loads via L3. Only
//     cross-XCD state: ~2 MB/step (vs round-5's 35 MB/step all-sc1).
//   - x / weights / biases: immutable -> plain cached loads.
//
// Blocks self-organize by physical XCD: s_getreg(HW_REG_XCC_ID) [HW-verified
// on MI355X, learn_hip m09]. If labels don't form exactly 8 pools of 32, ALL
// blocks switch to fallback mode (everything sc1) — correct on any mapping.
//
// Decomposition: 256 blocks x 512 thr (1 block/CU by VGPR; 32 blocks/XCD).
//   xcd -> l = xcd&1, batch group g = xcd>>1 (batches 8g..8g+8).
//   Block slot s in [0,32): gates cols [32s,32s+32) (4/wave), cand cols
//   [16s,16s+16) (2/wave). Weights VGPR-resident (96 floats/lane), loaded
//   once from the ORIGINAL Wg/Wc layout (one-time uncoalesced, ~40 us).
//   K=1024 split: lane owns k in {2*lane + 128*i} pairs (float2).
//   Per phase, wave w stages row (b0+w) into LDS once; all waves read LDS.
//   Dots finished with select-merge butterflies (red4/red2).
//
// Barrier: round-5 two-level tree (32 leaves + root), monotonic targets.
//
// ws (floats): h0@0 h1@16384 y0@32768[2][32][512] rh@65536[2][32][512]
//   uu@98304 ctrl(int)@131072 [pools16, order@16, fb@17, labelMap@18..33]
//   bar(int)@131136 [leaves 32x4, root@128]. Total < 520 KB.
// ---------------------------------------------------------------------------

__device__ __forceinline__ float2 ld2_sc1(const float* p) {
    double d = __hip_atomic_load((const double*)p, __ATOMIC_RELAXED, AG);
    return __builtin_bit_cast(float2, d);
}
__device__ __forceinline__ void st1_sc1(float* p, float v) {
    __hip_atomic_store(p, v, __ATOMIC_RELAXED, AG);
}
__device__ __forceinline__ int ldi_sc1(const int* p) {
    return __hip_atomic_load(p, __ATOMIC_RELAXED, AG);
}

// Four 8B loads that bypass L1 but HIT the local L2 (sc0), one waitcnt.
__device__ __forceinline__ void ld2_sc0_x4(const float* p0, const float* p1,
                                           const float* p2, const float* p3,
                                           float2& v0, float2& v1,
                                           float2& v2, float2& v3) {
    asm volatile(
        "global_load_dwordx2 %0, %4, off sc0\n\t"
        "global_load_dwordx2 %1, %5, off sc0\n\t"
        "global_load_dwordx2 %2, %6, off sc0\n\t"
        "global_load_dwordx2 %3, %7, off sc0\n\t"
        "s_waitcnt vmcnt(0)"
        : "=v"(v0), "=v"(v1), "=v"(v2), "=v"(v3)
        : "v"(p0), "v"(p1), "v"(p2), "v"(p3)
        : "memory");
}

// Reduce 4 accs over 64 lanes; lane ends with total of acc[lane&3]. (r5-proven)
__device__ __forceinline__ float red4(float a0, float a1, float a2, float a3,
                                      int lane) {
    const bool b1 = lane & 1, b2 = lane & 2;
    float p0 = (b1 ? a1 : a0) + __shfl_xor((b1 ? a0 : a1), 1, 64);
    float p1 = (b1 ? a3 : a2) + __shfl_xor((b1 ? a2 : a3), 1, 64);
    float r = (b2 ? p1 : p0) + __shfl_xor((b2 ? p0 : p1), 2, 64);
    r += __shfl_xor(r, 4, 64);
    r += __shfl_xor(r, 8, 64);
    r += __shfl_xor(r, 16, 64);
    r += __shfl_xor(r, 32, 64);
    return r;
}
// Reduce 2 accs; lane ends with total of acc[lane&1].
__device__ __forceinline__ float red2(float a0, float a1, int lane) {
    const bool b1 = lane & 1;
    float r = (b1 ? a1 : a0) + __shfl_xor((b1 ? a0 : a1), 1, 64);
    r += __shfl_xor(r, 2, 64);
    r += __shfl_xor(r, 4, 64);
    r += __shfl_xor(r, 8, 64);
    r += __shfl_xor(r, 16, 64);
    r += __shfl_xor(r, 32, 64);
    return r;
}

// Two-level tree barrier (round-5 proven): leaves barb[4*(bid&31)], root barb[128].
__device__ __forceinline__ void gbar(int* barb, int bid, int nbar) {
    __syncthreads();  // drains vmcnt -> this block's stores committed (L2/L3)
    if (threadIdx.x == 0) {
        __hip_atomic_fetch_add(&barb[(bid & 31) * 4], 1, __ATOMIC_RELAXED, AG);
        if (bid < 32) {
            const int lt = nbar * 8;
            while (__hip_atomic_load(&barb[bid * 4], __ATOMIC_RELAXED, AG) < lt)
                __builtin_amdgcn_s_sleep(1);
            __hip_atomic_fetch_add(&barb[128], 1, __ATOMIC_RELAXED, AG);
        }
        const int rt = nbar * 32;
        while (__hip_atomic_load(&barb[128], __ATOMIC_RELAXED, AG) < rt)
            __builtin_amdgcn_s_sleep(1);
    }
    __syncthreads();
}

__global__ __launch_bounds__(NTHR, 2) void rnn_persist(
    const float* __restrict__ x, const int* __restrict__ seq_lens,
    const float* __restrict__ Wg, const float* __restrict__ bg,
    const float* __restrict__ Wc, const float* __restrict__ bc,
    float* __restrict__ out, float* __restrict__ ws) {
    __shared__ float ldsA[8][1024];  // per batch: [input 512 | h 512]
    __shared__ float ldsB[8][512];   // rh rows
    __shared__ float ldsU[8][512];   // uu rows
    __shared__ int shi[4];

    float* h0 = ws;
    float* h1 = ws + 16384;
    float* y0 = ws + 32768;
    float* rh = ws + 65536;
    float* uu = ws + 98304;
    int* ctrl = (int*)(ws + 131072);  // pools[16], order@16, fb@17, map@18..33
    int* barb = (int*)(ws + 131136);

    const int tid = threadIdx.x, bid = blockIdx.x;
    const int w = tid >> 6, lane = tid & 63;

    // ---- self-organization by physical XCD ----
    if (tid == 0) {
        int xcc;
        asm volatile("s_getreg_b32 %0, hwreg(HW_REG_XCC_ID)" : "=s"(xcc));
        xcc &= 15;
        int slot = __hip_atomic_fetch_add(&ctrl[xcc], 1, __ATOMIC_RELAXED, AG);
        shi[0] = xcc; shi[1] = slot;
    }
    __syncthreads();
    gbar(barb, bid, 1);
    if (tid == 0) {
        if (ldi_sc1(&ctrl[shi[0]]) != 32)
            __hip_atomic_store(&ctrl[17], 1, __ATOMIC_RELAXED, AG);
        if (shi[1] == 0) {
            int ord = __hip_atomic_fetch_add(&ctrl[16], 1, __ATOMIC_RELAXED, AG);
            __hip_atomic_store(&ctrl[18 + shi[0]], ord + 1, __ATOMIC_RELAXED, AG);
        }
    }
    gbar(barb, bid, 2);
    if (tid == 0) {
        int fbf = ldi_sc1(&ctrl[17]);
        if (ldi_sc1(&ctrl[16]) != 8) fbf = 1;  // must be exactly 8 labels
        int xi, sl;
        if (fbf) { xi = bid & 7; sl = bid >> 3; }
        else     { xi = ldi_sc1(&ctrl[18 + shi[0]]) - 1; sl = shi[1]; }
        shi[2] = fbf; shi[3] = xi; shi[1] = sl;
    }
    __syncthreads();
    const int fb = shi[2];
    const int xcd = shi[3];
    const int slot = shi[1];
    const int l = xcd & 1;
    const int b0 = (xcd >> 1) * 8;        // this XCD's batches [b0, b0+8)
    const int gj0 = slot * 32 + w * 4;    // this wave's 4 gate cols
    const int cm0 = slot * 16 + w * 2;    // this wave's 2 cand cols
    const int kb = 2 * lane;              // per-lane k base (float2 pairs)

    float* __restrict__ hl = l ? h1 : h0;
    float* __restrict__ rhl = rh + (size_t)l * (BB * HH);
    float* __restrict__ uul = uu + (size_t)l * (BB * HH);

    // ---- one-time weight load into VGPRs (original layout, uncoalesced) ----
    // wg[c][i] = Wg[l][kb+128i .. +1][gj0+c]; k halves contiguous (in|h).
    float2 wg[4][8];
#pragma unroll
    for (int c = 0; c < 4; ++c)
#pragma unroll
        for (int i = 0; i < 8; ++i) {
            const size_t r = (size_t)l * 1024 + kb + (i << 7);
            wg[c][i].x = Wg[r * 1024 + gj0 + c];
            wg[c][i].y = Wg[(r + 1) * 1024 + gj0 + c];
        }
    float2 wc[2][8];
#pragma unroll
    for (int c = 0; c < 2; ++c)
#pragma unroll
        for (int i = 0; i < 8; ++i) {
            const size_t r = (size_t)l * 1024 + kb + (i << 7);
            wc[c][i].x = Wc[r * 512 + cm0 + c];
            wc[c][i].y = Wc[(r + 1) * 512 + cm0 + c];
        }
    const float bgj = bg[l * 1024 + gj0 + (lane & 3)];
    const float bcm = bc[l * 512 + cm0 + (lane & 1)];
    int sl_[8];
#pragma unroll
    for (int i = 0; i < 8; ++i) sl_[i] = seq_lens[b0 + i];

    int nbar = 3;
    for (int t = 0; t <= TT; ++t) {
        const int tt = t - l;
        const bool active = (tt >= 0) && (tt < TT);

        // ================= phase A: gates =================
        if (active) {
            {   // stage: wave w stages full row [in | h] of batch b0+w
                const int b = b0 + w;
                const float* inrow = l ? (y0 + ((size_t)((tt & 1) * BB + b)) * HH)
                                       : (x + ((size_t)b * TT + tt) * HH);
                const float* hrow = hl + (size_t)b * HH;
                float2 vi[4], vh[4];
                if (l == 0) {
#pragma unroll
                    for (int i = 0; i < 4; ++i)
                        vi[i] = *(const float2*)(inrow + kb + (i << 7));
                } else {
#pragma unroll
                    for (int i = 0; i < 4; ++i)
                        vi[i] = ld2_sc1(inrow + kb + (i << 7));
                }
                if (fb) {
#pragma unroll
                    for (int i = 0; i < 4; ++i)
                        vh[i] = ld2_sc1(hrow + kb + (i << 7));
                } else {
                    ld2_sc0_x4(hrow + kb, hrow + kb + 128, hrow + kb + 256,
                               hrow + kb + 384, vh[0], vh[1], vh[2], vh[3]);
                }
#pragma unroll
                for (int i = 0; i < 4; ++i) {
                    *(float2*)&ldsA[w][kb + (i << 7)] = vi[i];
                    *(float2*)&ldsA[w][512 + kb + (i << 7)] = vh[i];
                }
            }
            __syncthreads();
#pragma unroll 2
            for (int bi = 0; bi < 8; ++bi) {
                float2 v[8];
#pragma unroll
                for (int i = 0; i < 8; ++i)
                    v[i] = *(const float2*)&ldsA[bi][kb + (i << 7)];
                float a0 = 0, a1 = 0, a2 = 0, a3 = 0;
#pragma unroll
                for (int i = 0; i < 8; ++i) {
                    a0 = fmaf(v[i].y, wg[0][i].y, fmaf(v[i].x, wg[0][i].x, a0));
                    a1 = fmaf(v[i].y, wg[1][i].y, fmaf(v[i].x, wg[1][i].x, a1));
                    a2 = fmaf(v[i].y, wg[2][i].y, fmaf(v[i].x, wg[2][i].x, a2));
                    a3 = fmaf(v[i].y, wg[3][i].y, fmaf(v[i].x, wg[3][i].x, a3));
                }
                const float sum = red4(a0, a1, a2, a3, lane);
                if (lane < 4) {
                    const int j = gj0 + lane;
                    const int b = b0 + bi;
                    const float gg = 1.0f / (1.0f + __expf(-(sum + bgj)));
                    if (gj0 < HH) {
                        const float val = gg * ldsA[bi][512 + j];
                        if (fb) st1_sc1(rhl + (size_t)b * HH + j, val);
                        else rhl[(size_t)b * HH + j] = val;
                    } else {
                        if (fb) st1_sc1(uul + (size_t)b * HH + (j - HH), gg);
                        else uul[(size_t)b * HH + (j - HH)] = gg;
                    }
                }
            }
        }
        gbar(barb, bid, nbar); ++nbar;

        // ================= phase B: candidate + update =================
        if (active) {
            {   // stage rh + uu rows of batch b0+w
                const int b = b0 + w;
                const float* rrow = rhl + (size_t)b * HH;
                const float* urow = uul + (size_t)b * HH;
                float2 vr[4], vu[4];
                if (fb) {
#pragma unroll
                    for (int i = 0; i < 4; ++i) {
                        vr[i] = ld2_sc1(rrow + kb + (i << 7));
                        vu[i] = ld2_sc1(urow + kb + (i << 7));
                    }
                } else {
                    ld2_sc0_x4(rrow + kb, rrow + kb + 128, rrow + kb + 256,
                               rrow + kb + 384, vr[0], vr[1], vr[2], vr[3]);
                    ld2_sc0_x4(urow + kb, urow + kb + 128, urow + kb + 256,
                               urow + kb + 384, vu[0], vu[1], vu[2], vu[3]);
                }
#pragma unroll
                for (int i = 0; i < 4; ++i) {
                    *(float2*)&ldsB[w][kb + (i << 7)] = vr[i];
                    *(float2*)&ldsU[w][kb + (i << 7)] = vu[i];
                }
            }
            __syncthreads();
#pragma unroll 2
            for (int bi = 0; bi < 8; ++bi) {
                float2 v[8];
#pragma unroll
                for (int i = 0; i < 4; ++i)
                    v[i] = *(const float2*)&ldsA[bi][kb + (i << 7)];
#pragma unroll
                for (int i = 0; i < 4; ++i)
                    v[4 + i] = *(const float2*)&ldsB[bi][kb + (i << 7)];
                float a0 = 0, a1 = 0;
#pragma unroll
                for (int i = 0; i < 8; ++i) {
                    a0 = fmaf(v[i].y, wc[0][i].y, fmaf(v[i].x, wc[0][i].x, a0));
                    a1 = fmaf(v[i].y, wc[1][i].y, fmaf(v[i].x, wc[1][i].x, a1));
                }
                const float sum = red2(a0, a1, lane);
                if (lane < 2) {
                    const int m = cm0 + lane;
                    const int b = b0 + bi;
                    const float cv = tanhf(sum + bcm);
                    const float u = ldsU[bi][m];
                    const float hold = ldsA[bi][512 + m];
                    const bool act = tt < sl_[bi];
                    const float hn = u * hold + (1.0f - u) * cv;
                    const float hstore = act ? hn : hold;
                    if (fb) st1_sc1(hl + (size_t)b * HH + m, hstore);
                    else hl[(size_t)b * HH + m] = hstore;
                    const float yv = act ? hn : 0.0f;
                    if (l == 0)
                        st1_sc1(y0 + ((size_t)((tt & 1) * BB + b)) * HH + m, yv);
                    else
                        out[((size_t)b * TT + tt) * HH + m] = yv;
                }
            }
        }
        gbar(barb, bid, nbar); ++nbar;
    }
}

extern "C" void kernel_launch(void* const* d_in, const int* in_sizes, int n_in,
                              void* d_out, int out_size, void* d_ws, size_t ws_size,
                              hipStream_t stream) {
    const float* x = (const float*)d_in[0];
    const int* seq_lens = (const int*)d_in[1];
    const float* Wg = (const float*)d_in[2];
    const float* bg = (const float*)d_in[3];
    const float* Wc = (const float*)d_in[4];
    const float* bc = (const float*)d_in[5];
    float* out = (float*)d_out;
    float* ws = (float*)d_ws;

    // zero h0/h1 + scratch + ctrl + barrier counters every launch
    hipMemsetAsync(ws, 0, 131400 * sizeof(float), stream);

    rnn_persist<<<NBLK, NTHR, 0, stream>>>(x, seq_lens, Wg, bg, Wc, bc, out, ws);
}

// Round 9
// 6867.661 us; speedup vs baseline: 2.9770x; 1.3135x over previous
//
#include <hip/hip_runtime.h>
#include <cstddef>

#define BB 32
#define TT 512
#define HH 512
#define NBLK 256
#define NTHR 512
#define YD 16  // y0 ring depth (L0 may run up to 16 steps ahead of L1)
#define AG __HIP_MEMORY_SCOPE_AGENT

// ---------------------------------------------------------------------------
// Persistent GRU, round 8 = round 7's sync-scope reduction rebuilt on PROVEN
// primitives only (round-7 deadlock diagnosed as the non-sc1 atomic / sc0
// poll pairing: atomics likely execute at L3 while sc0 polls hit a stale
// clean line in the local L2 -> spin forever. That mechanism is removed.)
//
//   - Group = (layer, batch-group-of-8) = 32 blocks = one XCD (happy path).
//   - Group barrier: two-stage, ALL sc1 (proven rounds 4-6): 4 leaf lines
//     x 8 arrivals + root x 4 arrivals, group-private lines.
//   - Layer handoff: L1 gates phase A(t) on L0.root >= 8t+8 (L0 done B(t));
//     L0 gates phase B(t>=16) on L1.root >= 8t-124 (L1 consumed y0[t-16]).
//     The root counter doubles as the progress flag - no extra stores.
//   - Data protocol per round 6 (proven): XCD-local h/rh/uu = plain stores +
//     sc0 loads (local L2, FETCH-invisible); cross-XCD y0 = sc1 (L3);
//     immutable x/W/b = plain cached loads. Fallback (bad XCC mapping):
//     everything sc1, logical groups - correct on any mapping.
//
// ws (floats): h0@0[16384] h1@16384[16384]
//   ctrl(int)@32768[64] barb(int)@32832[160] xleaf(int)@33024[8*64]
//   xroot(int)@33536[8*16]  (zero region ends @33664)
//   y0@36864[16][32][512] rh@299008[2][32][512] uu@331776[2][32][512]
// ---------------------------------------------------------------------------

__device__ __forceinline__ float2 ld2_sc1(const float* p) {
    double d = __hip_atomic_load((const double*)p, __ATOMIC_RELAXED, AG);
    return __builtin_bit_cast(float2, d);
}
__device__ __forceinline__ void st1_sc1(float* p, float v) {
    __hip_atomic_store(p, v, __ATOMIC_RELAXED, AG);
}
__device__ __forceinline__ int ldi_sc1(const int* p) {
    return __hip_atomic_load(p, __ATOMIC_RELAXED, AG);
}
__device__ __forceinline__ void sti_sc1(int* p, int v) {
    __hip_atomic_store(p, v, __ATOMIC_RELAXED, AG);
}

// Four 8B loads, L1-bypass / local-L2 hit (round-6 proven).
__device__ __forceinline__ void ld2_sc0_x4(const float* p0, const float* p1,
                                           const float* p2, const float* p3,
                                           float2& v0, float2& v1,
                                           float2& v2, float2& v3) {
    asm volatile(
        "global_load_dwordx2 %0, %4, off sc0\n\t"
        "global_load_dwordx2 %1, %5, off sc0\n\t"
        "global_load_dwordx2 %2, %6, off sc0\n\t"
        "global_load_dwordx2 %3, %7, off sc0\n\t"
        "s_waitcnt vmcnt(0)"
        : "=v"(v0), "=v"(v1), "=v"(v2), "=v"(v3)
        : "v"(p0), "v"(p1), "v"(p2), "v"(p3)
        : "memory");
}

// Reduce 4 accs over 64 lanes; lane ends with total of acc[lane&3].
__device__ __forceinline__ float red4(float a0, float a1, float a2, float a3,
                                      int lane) {
    const bool b1 = lane & 1, b2 = lane & 2;
    float p0 = (b1 ? a1 : a0) + __shfl_xor((b1 ? a0 : a1), 1, 64);
    float p1 = (b1 ? a3 : a2) + __shfl_xor((b1 ? a2 : a3), 1, 64);
    float r = (b2 ? p1 : p0) + __shfl_xor((b2 ? p0 : p1), 2, 64);
    r += __shfl_xor(r, 4, 64);
    r += __shfl_xor(r, 8, 64);
    r += __shfl_xor(r, 16, 64);
    r += __shfl_xor(r, 32, 64);
    return r;
}
// Reduce 2 accs; lane ends with total of acc[lane&1].
__device__ __forceinline__ float red2(float a0, float a1, int lane) {
    const bool b1 = lane & 1;
    float r = (b1 ? a1 : a0) + __shfl_xor((b1 ? a0 : a1), 1, 64);
    r += __shfl_xor(r, 2, 64);
    r += __shfl_xor(r, 4, 64);
    r += __shfl_xor(r, 8, 64);
    r += __shfl_xor(r, 16, 64);
    r += __shfl_xor(r, 32, 64);
    return r;
}

// Global 2-level tree barrier (sc1) - prologue / self-org only (proven r5-7).
__device__ __forceinline__ void gbar(int* barb, int bid, int nbar) {
    __syncthreads();
    if (threadIdx.x == 0) {
        __hip_atomic_fetch_add(&barb[(bid & 31) * 4], 1, __ATOMIC_RELAXED, AG);
        if (bid < 32) {
            const int lt = nbar * 8;
            while (__hip_atomic_load(&barb[bid * 4], __ATOMIC_RELAXED, AG) < lt)
                __builtin_amdgcn_s_sleep(1);
            __hip_atomic_fetch_add(&barb[128], 1, __ATOMIC_RELAXED, AG);
        }
        const int rt = nbar * 32;
        while (__hip_atomic_load(&barb[128], __ATOMIC_RELAXED, AG) < rt)
            __builtin_amdgcn_s_sleep(1);
    }
    __syncthreads();
}

// Per-group barrier: 32 blocks, two-stage, ALL sc1 (proven primitive).
// leaf: 4 lines (64B apart), 8 arrivals each; root: 1 line, 4 arrivals.
// After phase ph (1-indexed): leaf[i] == 8*ph, root == 4*ph.
__device__ __forceinline__ void grpbar(int* leaf, int* root, int slot, int ph) {
    __syncthreads();  // each wave drains vmcnt before s_barrier -> stores done
    if (threadIdx.x == 0) {
        __hip_atomic_fetch_add(&leaf[(slot & 3) * 16], 1, __ATOMIC_RELAXED, AG);
        if (slot < 4) {
            const int lt = ph * 8;
            while (__hip_atomic_load(&leaf[slot * 16], __ATOMIC_RELAXED, AG) < lt)
                __builtin_amdgcn_s_sleep(1);
            __hip_atomic_fetch_add(root, 1, __ATOMIC_RELAXED, AG);
        }
        const int rt = ph * 4;
        while (__hip_atomic_load(root, __ATOMIC_RELAXED, AG) < rt)
            __builtin_amdgcn_s_sleep(1);
    }
    __syncthreads();
}

__global__ __launch_bounds__(NTHR, 2) void rnn_persist(
    const float* __restrict__ x, const int* __restrict__ seq_lens,
    const float* __restrict__ Wg, const float* __restrict__ bg,
    const float* __restrict__ Wc, const float* __restrict__ bc,
    float* __restrict__ out, float* __restrict__ ws) {
    __shared__ float ldsA[8][1024];  // per batch: [input 512 | h 512]
    __shared__ float ldsB[8][512];   // rh rows
    __shared__ float ldsU[8][512];   // uu rows
    __shared__ int shi[4];

    float* h0 = ws;
    float* h1 = ws + 16384;
    int* ctrl = (int*)(ws + 32768);   // pools[16], order@16, fb@17, map@18..33
    int* barb = (int*)(ws + 32832);   // global tree (prologue only)
    int* xleaf = (int*)(ws + 33024);  // 8 groups x 64 ints (4 lines x 16)
    int* xroot = (int*)(ws + 33536);  // 8 groups x 16 ints
    float* y0 = ws + 36864;           // [YD][BB][HH]
    float* rh = ws + 299008;
    float* uu = ws + 331776;

    const int tid = threadIdx.x, bid = blockIdx.x;
    const int w = tid >> 6, lane = tid & 63;

    // ---- self-organization by physical XCD (round-6 proven) ----
    if (tid == 0) {
        int xcc;
        asm volatile("s_getreg_b32 %0, hwreg(HW_REG_XCC_ID)" : "=s"(xcc));
        xcc &= 15;
        int slot = __hip_atomic_fetch_add(&ctrl[xcc], 1, __ATOMIC_RELAXED, AG);
        shi[0] = xcc; shi[1] = slot;
    }
    __syncthreads();
    gbar(barb, bid, 1);
    if (tid == 0) {
        if (ldi_sc1(&ctrl[shi[0]]) != 32)
            sti_sc1(&ctrl[17], 1);
        if (shi[1] == 0) {
            int ord = __hip_atomic_fetch_add(&ctrl[16], 1, __ATOMIC_RELAXED, AG);
            sti_sc1(&ctrl[18 + shi[0]], ord + 1);
        }
    }
    gbar(barb, bid, 2);
    if (tid == 0) {
        int fbf = ldi_sc1(&ctrl[17]);
        if (ldi_sc1(&ctrl[16]) != 8) fbf = 1;
        int xi, sl;
        if (fbf) { xi = bid & 7; sl = bid >> 3; }
        else     { xi = ldi_sc1(&ctrl[18 + shi[0]]) - 1; sl = shi[1]; }
        shi[2] = fbf; shi[3] = xi; shi[1] = sl;
    }
    __syncthreads();
    const int fb = shi[2];
    const int xcd = shi[3];   // logical group id 0..7
    const int slot = shi[1];  // 0..31 within group
    const int l = xcd & 1;
    const int g = xcd >> 1;
    const int b0 = g * 8;
    const int gj0 = slot * 32 + w * 4;
    const int cm0 = slot * 16 + w * 2;
    const int kb = 2 * lane;

    float* __restrict__ hl = l ? h1 : h0;
    float* __restrict__ rhl = rh + (size_t)l * (BB * HH);
    float* __restrict__ uul = uu + (size_t)l * (BB * HH);
    int* myleaf = xleaf + xcd * 64;
    int* myroot = xroot + xcd * 16;
    // peer group: same batch-group, other layer
    int* peerroot = xroot + (g * 2 + (1 - l)) * 16;

    // ---- one-time weight load into registers (original layout) ----
    float2 wg[4][8];
#pragma unroll
    for (int c = 0; c < 4; ++c)
#pragma unroll
        for (int i = 0; i < 8; ++i) {
            const size_t r = (size_t)l * 1024 + kb + (i << 7);
            wg[c][i].x = Wg[r * 1024 + gj0 + c];
            wg[c][i].y = Wg[(r + 1) * 1024 + gj0 + c];
        }
    float2 wc[2][8];
#pragma unroll
    for (int c = 0; c < 2; ++c)
#pragma unroll
        for (int i = 0; i < 8; ++i) {
            const size_t r = (size_t)l * 1024 + kb + (i << 7);
            wc[c][i].x = Wc[r * 512 + cm0 + c];
            wc[c][i].y = Wc[(r + 1) * 512 + cm0 + c];
        }
    const float bgj = bg[l * 1024 + gj0 + (lane & 3)];
    const float bcm = bc[l * 512 + cm0 + (lane & 1)];
    int sl_[8];
#pragma unroll
    for (int i = 0; i < 8; ++i) sl_[i] = seq_lens[b0 + i];

    int ph = 0;
    for (int t = 0; t < TT; ++t) {
        // ================= phase A: gates =================
        // L1 gate: y0[t] produced <=> L0 group finished phase B(t):
        // L0 phases done = 2t+2 -> L0.root >= 4*(2t+2) = 8t+8.
        if (l == 1) {
            if (tid == 0) {
                const int need = 8 * t + 8;
                while (ldi_sc1(peerroot) < need) __builtin_amdgcn_s_sleep(2);
            }
            __syncthreads();
        }
        {   // stage: wave w stages full row [in | h] of batch b0+w
            const int b = b0 + w;
            const float* inrow = l ? (y0 + ((size_t)((t & (YD - 1)) * BB + b)) * HH)
                                   : (x + ((size_t)b * TT + t) * HH);
            const float* hrow = hl + (size_t)b * HH;
            float2 vi[4], vh[4];
            if (l == 0) {
#pragma unroll
                for (int i = 0; i < 4; ++i)
                    vi[i] = *(const float2*)(inrow + kb + (i << 7));
            } else {
#pragma unroll
                for (int i = 0; i < 4; ++i)
                    vi[i] = ld2_sc1(inrow + kb + (i << 7));
            }
            if (fb) {
#pragma unroll
                for (int i = 0; i < 4; ++i)
                    vh[i] = ld2_sc1(hrow + kb + (i << 7));
            } else {
                ld2_sc0_x4(hrow + kb, hrow + kb + 128, hrow + kb + 256,
                           hrow + kb + 384, vh[0], vh[1], vh[2], vh[3]);
            }
#pragma unroll
            for (int i = 0; i < 4; ++i) {
                *(float2*)&ldsA[w][kb + (i << 7)] = vi[i];
                *(float2*)&ldsA[w][512 + kb + (i << 7)] = vh[i];
            }
        }
        __syncthreads();
#pragma unroll 2
        for (int bi = 0; bi < 8; ++bi) {
            float2 v[8];
#pragma unroll
            for (int i = 0; i < 8; ++i)
                v[i] = *(const float2*)&ldsA[bi][kb + (i << 7)];
            float a0 = 0, a1 = 0, a2 = 0, a3 = 0;
#pragma unroll
            for (int i = 0; i < 8; ++i) {
                a0 = fmaf(v[i].y, wg[0][i].y, fmaf(v[i].x, wg[0][i].x, a0));
                a1 = fmaf(v[i].y, wg[1][i].y, fmaf(v[i].x, wg[1][i].x, a1));
                a2 = fmaf(v[i].y, wg[2][i].y, fmaf(v[i].x, wg[2][i].x, a2));
                a3 = fmaf(v[i].y, wg[3][i].y, fmaf(v[i].x, wg[3][i].x, a3));
            }
            const float sum = red4(a0, a1, a2, a3, lane);
            if (lane < 4) {
                const int j = gj0 + lane;
                const int b = b0 + bi;
                const float gg = 1.0f / (1.0f + __expf(-(sum + bgj)));
                if (gj0 < HH) {
                    const float val = gg * ldsA[bi][512 + j];
                    if (fb) st1_sc1(rhl + (size_t)b * HH + j, val);
                    else rhl[(size_t)b * HH + j] = val;
                } else {
                    if (fb) st1_sc1(uul + (size_t)b * HH + (j - HH), gg);
                    else uul[(size_t)b * HH + (j - HH)] = gg;
                }
            }
        }
        ++ph; grpbar(myleaf, myroot, slot, ph);

        // ================= phase B: candidate + update =================
        // L0 gate: don't overwrite y0 slot until L1 consumed y0[t-16]:
        // L1 finished phase A(t-16) -> L1 phases done >= 2(t-16)+1
        // -> L1.root >= 4*(2t-31) = 8t-124.
        if (l == 0 && t >= YD) {
            if (tid == 0) {
                const int need = 8 * t - 124;
                while (ldi_sc1(peerroot) < need) __builtin_amdgcn_s_sleep(2);
            }
            __syncthreads();
        }
        {   // stage rh + uu rows of batch b0+w
            const int b = b0 + w;
            const float* rrow = rhl + (size_t)b * HH;
            const float* urow = uul + (size_t)b * HH;
            float2 vr[4], vu[4];
            if (fb) {
#pragma unroll
                for (int i = 0; i < 4; ++i) {
                    vr[i] = ld2_sc1(rrow + kb + (i << 7));
                    vu[i] = ld2_sc1(urow + kb + (i << 7));
                }
            } else {
                ld2_sc0_x4(rrow + kb, rrow + kb + 128, rrow + kb + 256,
                           rrow + kb + 384, vr[0], vr[1], vr[2], vr[3]);
                ld2_sc0_x4(urow + kb, urow + kb + 128, urow + kb + 256,
                           urow + kb + 384, vu[0], vu[1], vu[2], vu[3]);
            }
#pragma unroll
            for (int i = 0; i < 4; ++i) {
                *(float2*)&ldsB[w][kb + (i << 7)] = vr[i];
                *(float2*)&ldsU[w][kb + (i << 7)] = vu[i];
            }
        }
        __syncthreads();
#pragma unroll 2
        for (int bi = 0; bi < 8; ++bi) {
            float2 v[8];
#pragma unroll
            for (int i = 0; i < 4; ++i)
                v[i] = *(const float2*)&ldsA[bi][kb + (i << 7)];
#pragma unroll
            for (int i = 0; i < 4; ++i)
                v[4 + i] = *(const float2*)&ldsB[bi][kb + (i << 7)];
            float a0 = 0, a1 = 0;
#pragma unroll
            for (int i = 0; i < 8; ++i) {
                a0 = fmaf(v[i].y, wc[0][i].y, fmaf(v[i].x, wc[0][i].x, a0));
                a1 = fmaf(v[i].y, wc[1][i].y, fmaf(v[i].x, wc[1][i].x, a1));
            }
            const float sum = red2(a0, a1, lane);
            if (lane < 2) {
                const int m = cm0 + lane;
                const int b = b0 + bi;
                const float cv = tanhf(sum + bcm);
                const float u = ldsU[bi][m];
                const float hold = ldsA[bi][512 + m];
                const bool act = t < sl_[bi];
                const float hn = u * hold + (1.0f - u) * cv;
                const float hstore = act ? hn : hold;
                if (fb) st1_sc1(hl + (size_t)b * HH + m, hstore);
                else hl[(size_t)b * HH + m] = hstore;
                const float yv = act ? hn : 0.0f;
                if (l == 0)
                    st1_sc1(y0 + ((size_t)((t & (YD - 1)) * BB + b)) * HH + m, yv);
                else
                    out[((size_t)b * TT + t) * HH + m] = yv;
            }
        }
        ++ph; grpbar(myleaf, myroot, slot, ph);
    }
}

extern "C" void kernel_launch(void* const* d_in, const int* in_sizes, int n_in,
                              void* d_out, int out_size, void* d_ws, size_t ws_size,
                              hipStream_t stream) {
    const float* x = (const float*)d_in[0];
    const int* seq_lens = (const int*)d_in[1];
    const float* Wg = (const float*)d_in[2];
    const float* bg = (const float*)d_in[3];
    const float* Wc = (const float*)d_in[4];
    const float* bc = (const float*)d_in[5];
    float* out = (float*)d_out;
    float* ws = (float*)d_ws;

    // zero h0/h1 + ctrl + all barrier counters every launch (graph replays
    // deterministic); y0/rh/uu are produced-before-consumed each launch.
    hipMemsetAsync(ws, 0, 33664 * sizeof(float), stream);

    rnn_persist<<<NBLK, NTHR, 0, stream>>>(x, seq_lens, Wg, bg, Wc, bc, out, ws);
}

// Round 12
// 6394.020 us; speedup vs baseline: 3.1975x; 1.0741x over previous
//
#include <hip/hip_runtime.h>
#include <cstddef>

#define BB 32
#define TT 512
#define HH 512
#define NBLK 256
#define NTHR 512
#define YD 16  // y0 ring depth
#define AG __HIP_MEMORY_SCOPE_AGENT

// ---------------------------------------------------------------------------
// Persistent GRU, round 11 = round 10 with the s_sleep constant-arg compile
// fix (template parameter). Design unchanged:
//
//   Arrive: __syncthreads (drains vmcnt -> stores globally visible), then one
//     relaxed sc1 store of the phase number into this block's slot. Executes
//     EVERY phase including the last -> no end-of-loop publication hole.
//   Group wait: wave 0 polls own group's 32 slots (lane L reads slot[L&31],
//     one coalesced txn), __ballot(v>=need)==all. No RMWs anywhere.
//   Cross-layer gates (direct peer-slot polls):
//     L1 A(t): all L0 slots >= 2t+2   (L0 arrived B(t) -> y0[t] complete)
//     L0 B(t>=16): all L1 slots >= 2t-31 (L1 arrived A(t-16) -> ring free)
//   Liveness: waits only on peer's past arrivals; arrivals unconditional ->
//     no circular wait. WAR safety: all state stores sit after the wait that
//     proves readers are done (same ordering as rounds 8/9).
//   Split-phase overlap: stage in-row -> in-half partial accs (K=512, x/y0
//     only) -> WAIT -> stage h/rh half -> finish dot -> epilogue stores.
//   Data protocol (rounds 6/8 proven): XCD-local h/rh/uu = plain stores +
//     sc0 loads (local L2); cross-XCD y0 = sc1 (L3); x/W/b plain cached.
//   Fallback (bad XCC mapping): logical groups, everything sc1 — correct on
//     any mapping; same gate structure -> deadlock-free.
//
// ws (floats): h0@0[16384] h1@16384[16384] ctrl(int)@32768[64]
//   barb(int)@32832[192] pslot(int)@33024[8 groups x 32]
//   (zero region ends @33280)
//   y0@36864[16][32][512] rh@299008[2][32][512] uu@331776[2][32][512]
// ---------------------------------------------------------------------------

__device__ __forceinline__ float2 ld2_sc1(const float* p) {
    double d = __hip_atomic_load((const double*)p, __ATOMIC_RELAXED, AG);
    return __builtin_bit_cast(float2, d);
}
__device__ __forceinline__ void st1_sc1(float* p, float v) {
    __hip_atomic_store(p, v, __ATOMIC_RELAXED, AG);
}
__device__ __forceinline__ int ldi_sc1(const int* p) {
    return __hip_atomic_load(p, __ATOMIC_RELAXED, AG);
}
__device__ __forceinline__ void sti_sc1(int* p, int v) {
    __hip_atomic_store(p, v, __ATOMIC_RELAXED, AG);
}

// Four 8B loads, L1-bypass / local-L2 hit (round-6 proven).
__device__ __forceinline__ void ld2_sc0_x4(const float* p0, const float* p1,
                                           const float* p2, const float* p3,
                                           float2& v0, float2& v1,
                                           float2& v2, float2& v3) {
    asm volatile(
        "global_load_dwordx2 %0, %4, off sc0\n\t"
        "global_load_dwordx2 %1, %5, off sc0\n\t"
        "global_load_dwordx2 %2, %6, off sc0\n\t"
        "global_load_dwordx2 %3, %7, off sc0\n\t"
        "s_waitcnt vmcnt(0)"
        : "=v"(v0), "=v"(v1), "=v"(v2), "=v"(v3)
        : "v"(p0), "v"(p1), "v"(p2), "v"(p3)
        : "memory");
}

// Reduce 4 accs over 64 lanes; lane ends with total of acc[lane&3].
__device__ __forceinline__ float red4(float a0, float a1, float a2, float a3,
                                      int lane) {
    const bool b1 = lane & 1, b2 = lane & 2;
    float p0 = (b1 ? a1 : a0) + __shfl_xor((b1 ? a0 : a1), 1, 64);
    float p1 = (b1 ? a3 : a2) + __shfl_xor((b1 ? a2 : a3), 1, 64);
    float r = (b2 ? p1 : p0) + __shfl_xor((b2 ? p0 : p1), 2, 64);
    r += __shfl_xor(r, 4, 64);
    r += __shfl_xor(r, 8, 64);
    r += __shfl_xor(r, 16, 64);
    r += __shfl_xor(r, 32, 64);
    return r;
}
// Reduce 2 accs; lane ends with total of acc[lane&1].
__device__ __forceinline__ float red2(float a0, float a1, int lane) {
    const bool b1 = lane & 1;
    float r = (b1 ? a1 : a0) + __shfl_xor((b1 ? a0 : a1), 1, 64);
    r += __shfl_xor(r, 2, 64);
    r += __shfl_xor(r, 4, 64);
    r += __shfl_xor(r, 8, 64);
    r += __shfl_xor(r, 16, 64);
    r += __shfl_xor(r, 32, 64);
    return r;
}

// Global 2-level tree barrier (sc1 RMW) - prologue / self-org only (proven).
__device__ __forceinline__ void gbar(int* barb, int bid, int nbar) {
    __syncthreads();
    if (threadIdx.x == 0) {
        __hip_atomic_fetch_add(&barb[(bid & 31) * 4], 1, __ATOMIC_RELAXED, AG);
        if (bid < 32) {
            const int lt = nbar * 8;
            while (__hip_atomic_load(&barb[bid * 4], __ATOMIC_RELAXED, AG) < lt)
                __builtin_amdgcn_s_sleep(1);
            __hip_atomic_fetch_add(&barb[128], 1, __ATOMIC_RELAXED, AG);
        }
        const int rt = nbar * 32;
        while (__hip_atomic_load(&barb[128], __ATOMIC_RELAXED, AG) < rt)
            __builtin_amdgcn_s_sleep(1);
    }
    __syncthreads();
}

// Ballot-poll until ALL 32 slot words of `slots` reach `need`.
template <int SLP>
__device__ __forceinline__ void poll_slots(int* slots, int need) {
    if (threadIdx.x < 64) {
        for (;;) {
            const int v = __hip_atomic_load(&slots[threadIdx.x & 31],
                                            __ATOMIC_RELAXED, AG);
            if (__ballot(v >= need) == ~0ull) break;
            __builtin_amdgcn_s_sleep(SLP);
        }
    }
    __syncthreads();
}

// Arrive: drain this block's stores, then one sc1 store (no RMW).
__device__ __forceinline__ void arrive(int* myslot, int val) {
    __syncthreads();  // compiler drains vmcnt(0) before s_barrier
    if (threadIdx.x == 0) sti_sc1(myslot, val);
}

__global__ __launch_bounds__(NTHR, 2) void rnn_persist(
    const float* __restrict__ x, const int* __restrict__ seq_lens,
    const float* __restrict__ Wg, const float* __restrict__ bg,
    const float* __restrict__ Wc, const float* __restrict__ bc,
    float* __restrict__ out, float* __restrict__ ws) {
    __shared__ float ldsA[8][1024];  // per batch: [input 512 | h 512]
    __shared__ float ldsB[8][512];   // rh rows
    __shared__ float ldsU[8][512];   // uu rows
    __shared__ int shi[4];

    float* h0 = ws;
    float* h1 = ws + 16384;
    int* ctrl = (int*)(ws + 32768);   // pools[16], order@16, fb@17, map@18..33
    int* barb = (int*)(ws + 32832);   // global tree (prologue only)
    int* pslot = (int*)(ws + 33024);  // 8 groups x 32 ints
    float* y0 = ws + 36864;           // [YD][BB][HH]
    float* rh = ws + 299008;
    float* uu = ws + 331776;

    const int tid = threadIdx.x, bid = blockIdx.x;
    const int w = tid >> 6, lane = tid & 63;

    // ---- self-organization by physical XCD (rounds 6/8 proven) ----
    if (tid == 0) {
        int xcc;
        asm volatile("s_getreg_b32 %0, hwreg(HW_REG_XCC_ID)" : "=s"(xcc));
        xcc &= 15;
        int slot = __hip_atomic_fetch_add(&ctrl[xcc], 1, __ATOMIC_RELAXED, AG);
        shi[0] = xcc; shi[1] = slot;
    }
    __syncthreads();
    gbar(barb, bid, 1);
    if (tid == 0) {
        if (ldi_sc1(&ctrl[shi[0]]) != 32)
            sti_sc1(&ctrl[17], 1);
        if (shi[1] == 0) {
            int ord = __hip_atomic_fetch_add(&ctrl[16], 1, __ATOMIC_RELAXED, AG);
            sti_sc1(&ctrl[18 + shi[0]], ord + 1);
        }
    }
    gbar(barb, bid, 2);
    if (tid == 0) {
        int fbf = ldi_sc1(&ctrl[17]);
        if (ldi_sc1(&ctrl[16]) != 8) fbf = 1;
        int xi, sl;
        if (fbf) { xi = bid & 7; sl = bid >> 3; }
        else     { xi = ldi_sc1(&ctrl[18 + shi[0]]) - 1; sl = shi[1]; }
        shi[2] = fbf; shi[3] = xi; shi[1] = sl;
    }
    __syncthreads();
    const int fb = shi[2];
    const int xcd = shi[3];   // logical group id 0..7
    const int slot = shi[1];  // 0..31 within group
    const int l = xcd & 1;
    const int g = xcd >> 1;
    const int b0 = g * 8;
    const int gj0 = slot * 32 + w * 4;
    const int cm0 = slot * 16 + w * 2;
    const int kb = 2 * lane;

    float* __restrict__ hl = l ? h1 : h0;
    float* __restrict__ rhl = rh + (size_t)l * (BB * HH);
    float* __restrict__ uul = uu + (size_t)l * (BB * HH);
    int* myslots = pslot + xcd * 32;
    int* peerslots = pslot + (g * 2 + (1 - l)) * 32;

    // ---- one-time weight load into registers (original layout) ----
    float2 wg[4][8];
#pragma unroll
    for (int c = 0; c < 4; ++c)
#pragma unroll
        for (int i = 0; i < 8; ++i) {
            const size_t r = (size_t)l * 1024 + kb + (i << 7);
            wg[c][i].x = Wg[r * 1024 + gj0 + c];
            wg[c][i].y = Wg[(r + 1) * 1024 + gj0 + c];
        }
    float2 wc[2][8];
#pragma unroll
    for (int c = 0; c < 2; ++c)
#pragma unroll
        for (int i = 0; i < 8; ++i) {
            const size_t r = (size_t)l * 1024 + kb + (i << 7);
            wc[c][i].x = Wc[r * 512 + cm0 + c];
            wc[c][i].y = Wc[(r + 1) * 512 + cm0 + c];
        }
    const float bgj = bg[l * 1024 + gj0 + (lane & 3)];
    const float bcm = bc[l * 512 + cm0 + (lane & 1)];
    int sl_[8];
#pragma unroll
    for (int i = 0; i < 8; ++i) sl_[i] = seq_lens[b0 + i];

    for (int t = 0; t < TT; ++t) {
        // ================= phase A: gates =================
        // L1 gate: y0[t] produced <=> all L0 slots >= 2t+2 (L0 arrived B(t)).
        if (l == 1) poll_slots<2>(peerslots, 2 * t + 2);
        {   // stage in-row of batch b0+w (no group dependency)
            const int b = b0 + w;
            const float* inrow = l ? (y0 + ((size_t)((t & (YD - 1)) * BB + b)) * HH)
                                   : (x + ((size_t)b * TT + t) * HH);
            float2 vi[4];
            if (l == 0) {
#pragma unroll
                for (int i = 0; i < 4; ++i)
                    vi[i] = *(const float2*)(inrow + kb + (i << 7));
            } else {
#pragma unroll
                for (int i = 0; i < 4; ++i)
                    vi[i] = ld2_sc1(inrow + kb + (i << 7));
            }
#pragma unroll
            for (int i = 0; i < 4; ++i)
                *(float2*)&ldsA[w][kb + (i << 7)] = vi[i];
        }
        __syncthreads();
        // in-half partial accs (overlaps peers still finishing B(t-1))
        float aA0[8], aA1[8], aA2[8], aA3[8];
#pragma unroll
        for (int bi = 0; bi < 8; ++bi) {
            float s0 = 0, s1 = 0, s2 = 0, s3 = 0;
#pragma unroll
            for (int i = 0; i < 4; ++i) {
                const float2 v = *(const float2*)&ldsA[bi][kb + (i << 7)];
                s0 = fmaf(v.y, wg[0][i].y, fmaf(v.x, wg[0][i].x, s0));
                s1 = fmaf(v.y, wg[1][i].y, fmaf(v.x, wg[1][i].x, s1));
                s2 = fmaf(v.y, wg[2][i].y, fmaf(v.x, wg[2][i].x, s2));
                s3 = fmaf(v.y, wg[3][i].y, fmaf(v.x, wg[3][i].x, s3));
            }
            aA0[bi] = s0; aA1[bi] = s1; aA2[bi] = s2; aA3[bi] = s3;
        }
        // wait end-of-B(t-1): h(t) complete, rh/uu(t-1) fully consumed
        if (t > 0) poll_slots<1>(myslots, 2 * t);
        {   // stage h-half of batch b0+w (fresh after wait)
            const int b = b0 + w;
            const float* hrow = hl + (size_t)b * HH;
            float2 vh[4];
            if (fb) {
#pragma unroll
                for (int i = 0; i < 4; ++i)
                    vh[i] = ld2_sc1(hrow + kb + (i << 7));
            } else {
                ld2_sc0_x4(hrow + kb, hrow + kb + 128, hrow + kb + 256,
                           hrow + kb + 384, vh[0], vh[1], vh[2], vh[3]);
            }
#pragma unroll
            for (int i = 0; i < 4; ++i)
                *(float2*)&ldsA[w][512 + kb + (i << 7)] = vh[i];
        }
        __syncthreads();
#pragma unroll
        for (int bi = 0; bi < 8; ++bi) {
            float s0 = aA0[bi], s1 = aA1[bi], s2 = aA2[bi], s3 = aA3[bi];
#pragma unroll
            for (int i = 4; i < 8; ++i) {
                const float2 v = *(const float2*)&ldsA[bi][kb + (i << 7)];
                s0 = fmaf(v.y, wg[0][i].y, fmaf(v.x, wg[0][i].x, s0));
                s1 = fmaf(v.y, wg[1][i].y, fmaf(v.x, wg[1][i].x, s1));
                s2 = fmaf(v.y, wg[2][i].y, fmaf(v.x, wg[2][i].x, s2));
                s3 = fmaf(v.y, wg[3][i].y, fmaf(v.x, wg[3][i].x, s3));
            }
            const float sum = red4(s0, s1, s2, s3, lane);
            if (lane < 4) {
                const int j = gj0 + lane;
                const int b = b0 + bi;
                const float gg = 1.0f / (1.0f + __expf(-(sum + bgj)));
                if (gj0 < HH) {
                    const float val = gg * ldsA[bi][512 + j];
                    if (fb) st1_sc1(rhl + (size_t)b * HH + j, val);
                    else rhl[(size_t)b * HH + j] = val;
                } else {
                    if (fb) st1_sc1(uul + (size_t)b * HH + (j - HH), gg);
                    else uul[(size_t)b * HH + (j - HH)] = gg;
                }
            }
        }
        arrive(&myslots[slot], 2 * t + 1);

        // ================= phase B: candidate + update =================
        // in-half partial accs (in-row still in ldsA; overlaps peers' A(t))
        float aB0[8], aB1[8];
#pragma unroll
        for (int bi = 0; bi < 8; ++bi) {
            float s0 = 0, s1 = 0;
#pragma unroll
            for (int i = 0; i < 4; ++i) {
                const float2 v = *(const float2*)&ldsA[bi][kb + (i << 7)];
                s0 = fmaf(v.y, wc[0][i].y, fmaf(v.x, wc[0][i].x, s0));
                s1 = fmaf(v.y, wc[1][i].y, fmaf(v.x, wc[1][i].x, s1));
            }
            aB0[bi] = s0; aB1[bi] = s1;
        }
        // wait end-of-A(t): rh/uu(t) complete, h(t) fully consumed
        poll_slots<1>(myslots, 2 * t + 1);
        // L0 ring gate: L1 consumed y0[t-16] <=> all L1 slots >= 2t-31.
        if (l == 0 && t >= YD) poll_slots<2>(peerslots, 2 * t - 31);
        {   // stage rh + uu rows of batch b0+w
            const int b = b0 + w;
            const float* rrow = rhl + (size_t)b * HH;
            const float* urow = uul + (size_t)b * HH;
            float2 vr[4], vu[4];
            if (fb) {
#pragma unroll
                for (int i = 0; i < 4; ++i) {
                    vr[i] = ld2_sc1(rrow + kb + (i << 7));
                    vu[i] = ld2_sc1(urow + kb + (i << 7));
                }
            } else {
                ld2_sc0_x4(rrow + kb, rrow + kb + 128, rrow + kb + 256,
                           rrow + kb + 384, vr[0], vr[1], vr[2], vr[3]);
                ld2_sc0_x4(urow + kb, urow + kb + 128, urow + kb + 256,
                           urow + kb + 384, vu[0], vu[1], vu[2], vu[3]);
            }
#pragma unroll
            for (int i = 0; i < 4; ++i) {
                *(float2*)&ldsB[w][kb + (i << 7)] = vr[i];
                *(float2*)&ldsU[w][kb + (i << 7)] = vu[i];
            }
        }
        __syncthreads();
#pragma unroll
        for (int bi = 0; bi < 8; ++bi) {
            float s0 = aB0[bi], s1 = aB1[bi];
#pragma unroll
            for (int i = 0; i < 4; ++i) {
                const float2 v = *(const float2*)&ldsB[bi][kb + (i << 7)];
                s0 = fmaf(v.y, wc[0][i + 4].y, fmaf(v.x, wc[0][i + 4].x, s0));
                s1 = fmaf(v.y, wc[1][i + 4].y, fmaf(v.x, wc[1][i + 4].x, s1));
            }
            const float sum = red2(s0, s1, lane);
            if (lane < 2) {
                const int m = cm0 + lane;
                const int b = b0 + bi;
                const float cv = tanhf(sum + bcm);
                const float u = ldsU[bi][m];
                const float hold = ldsA[bi][512 + m];
                const bool act = t < sl_[bi];
                const float hn = u * hold + (1.0f - u) * cv;
                const float hstore = act ? hn : hold;
                if (fb) st1_sc1(hl + (size_t)b * HH + m, hstore);
                else hl[(size_t)b * HH + m] = hstore;
                const float yv = act ? hn : 0.0f;
                if (l == 0)
                    st1_sc1(y0 + ((size_t)((t & (YD - 1)) * BB + b)) * HH + m, yv);
                else
                    out[((size_t)b * TT + t) * HH + m] = yv;
            }
        }
        arrive(&myslots[slot], 2 * t + 2);
    }
}

extern "C" void kernel_launch(void* const* d_in, const int* in_sizes, int n_in,
                              void* d_out, int out_size, void* d_ws, size_t ws_size,
                              hipStream_t stream) {
    const float* x = (const float*)d_in[0];
    const int* seq_lens = (const int*)d_in[1];
    const float* Wg = (const float*)d_in[2];
    const float* bg = (const float*)d_in[3];
    const float* Wc = (const float*)d_in[4];
    const float* bc = (const float*)d_in[5];
    float* out = (float*)d_out;
    float* ws = (float*)d_ws;

    // zero h0/h1 + ctrl + prologue tree + slots every launch
    (void)hipMemsetAsync(ws, 0, 33280 * sizeof(float), stream);

    rnn_persist<<<NBLK, NTHR, 0, stream>>>(x, seq_lens, Wg, bg, Wc, bc, out, ws);
}